// Round 7
// baseline (211.268 us; speedup 1.0000x reference)
//
#include <hip/hip_runtime.h>
#include <hip/hip_bf16.h>

// MHA forward: B=2, T=2048, D=1024, H=16 (head dim 64), causal. fp32 I/O (sniffed).
// R15: R14's LPT attn-scheduling idea, WITHOUT the atomic work queue (suspected
//      in the R14 container failure; also replay-unsafe). Static LPT schedule:
//      grid = 640 blocks, one item each, blockIdx ordered descending by size
//      (24,22,...,2 iters; HW dispatches in blockIdx order as CUs free up, so
//      the 128 small tail items backfill). Items: qt<=11 whole; qt 12..15 split
//      into two key-halves — exact under no-max softmax (unnormalized O,l sum).
//      fp32 partials in dead ws (xb holds 256x32KB PO exactly; Wqb holds PL);
//      attn_combine (128 blocks) merges. Makespan bound 24 iters vs 34 before.
//      R9 attn body, R13 GEMM pipeline, original cvt all unchanged.

typedef __attribute__((ext_vector_type(8))) short bf16x8;   // MFMA A/B frag
typedef __attribute__((ext_vector_type(4))) float f32x4;    // MFMA C/D frag
typedef __attribute__((ext_vector_type(4))) short s16x4;    // 4 bf16 = b64

#define QSCALE 0.18033688011f   // (1/sqrt(64)) * log2(e)

// LPT item tables: blockIdx.x>>5 -> (qt, half). Sizes descending:
// 24,22,20,18,16,16,16,15,15,14,14,14,13,13,12,10,8,6,4,2.
// half: -1 whole, 0 keys[0,(qt+1)*64), 1 keys[(qt+1)*64,(2qt+2)*64).
__constant__ int QTA[20] = {11,10,9,8,15,15,7,14,14,13,13,6,12,12,5,4,3,2,1,0};
__constant__ int HFA[20] = {-1,-1,-1,-1,0,1,-1,0,1,0,1,-1,0,1,-1,-1,-1,-1,-1,-1};

__device__ __forceinline__ int sniff_f32(const void* p) {
    const unsigned short* u = (const unsigned short*)p;
    int c = 0;
    for (int i = 0; i < 256; ++i) {
        int e = (u[i] >> 7) & 0xFF;
        c += (e >= 0x90) ? 1 : 0;
    }
    return c > 8;
}

__device__ __forceinline__ void async_copy16(const void* g, void* l) {
    __builtin_amdgcn_global_load_lds(
        (const __attribute__((address_space(1))) void*)g,
        (__attribute__((address_space(3))) void*)l, 16, 0, 0);
}

// ---------------------------------------------------------------------------
// Convert pass (unchanged)
// ---------------------------------------------------------------------------
struct Cvt { const void* src; __hip_bfloat16* dst; int n; };
struct CvtPack { Cvt a[9]; };

__global__ __launch_bounds__(256) void cvt_bf16(CvtPack pk) {
    const Cvt c = pk.a[blockIdx.y];
    const int f32 = sniff_f32(c.src);
    const int stride = gridDim.x * 256 * 8;
    for (int idx = (blockIdx.x * 256 + threadIdx.x) * 8; idx < c.n; idx += stride) {
        if (f32) {
            const float* s = (const float*)c.src + idx;
            f32x4 a0 = *(const f32x4*)s;
            f32x4 a1 = *(const f32x4*)(s + 4);
            union { __hip_bfloat16 h[8]; bf16x8 v; } u;
#pragma unroll
            for (int e = 0; e < 4; e++) u.h[e]     = (__hip_bfloat16)a0[e];
#pragma unroll
            for (int e = 0; e < 4; e++) u.h[4 + e] = (__hip_bfloat16)a1[e];
            *(bf16x8*)&c.dst[idx] = u.v;
        } else {
            *(bf16x8*)&c.dst[idx] = *(const bf16x8*)((const __hip_bfloat16*)c.src + idx);
        }
    }
}

// ---------------------------------------------------------------------------
// 128x128 GEMM-BT, 2-phase prefetch (R13). MODE: 0 = bf16 row-major out,
// 1 = fp32 row-major out, 2 = bf16 out into VT[b][h][d][t] via LDS-staged
// coalesced writes.
// ---------------------------------------------------------------------------
template <int MODE>
__device__ __forceinline__ void gemm_async_body(
    const __hip_bfloat16* __restrict__ A, const __hip_bfloat16* __restrict__ W,
    const __hip_bfloat16* __restrict__ bias, void* __restrict__ C,
    int M, int N, int K, int bm, int bn, float outscale,
    __hip_bfloat16* smem)
{
    const int tid  = threadIdx.x;
    const int wave = tid >> 6;
    const int lane = tid & 63;
    const int quad = lane >> 4;
    const int l15  = lane & 15;
    const int wr   = wave >> 1;
    const int wc   = wave & 1;

    const int srow = wave * 16 + (lane >> 2);
    const int scol = (lane & 3) * 8;
    const __hip_bfloat16* gA0 = A + (size_t)(bm + srow) * K + scol;
    const __hip_bfloat16* gB0 = W + (size_t)(bn + srow) * K + scol;

    f32x4 acc[4][4];
#pragma unroll
    for (int i = 0; i < 4; i++)
#pragma unroll
        for (int j = 0; j < 4; j++) acc[i][j] = (f32x4)0.0f;

#define QSTAGE(buf, k0) { \
        __hip_bfloat16* d_ = smem + (buf) * 8192 + wave * 512; \
        async_copy16(gA0 + (k0), d_); \
        async_copy16(gA0 + (size_t)64 * K + (k0), d_ + 2048); \
        async_copy16(gB0 + (k0), d_ + 4096); \
        async_copy16(gB0 + (size_t)64 * K + (k0), d_ + 4096 + 2048); \
    }

    const int nt = K >> 5;
    QSTAGE(0, 0);
    for (int t = 0; t < nt; ++t) {
        const int buf = t & 1;
        const __hip_bfloat16* sA = smem + buf * 8192;
        const __hip_bfloat16* sB = sA + 4096;
        if (t + 1 < nt) {
            QSTAGE(1 - buf, (t + 1) * 32);
            asm volatile("s_waitcnt vmcnt(4)" ::: "memory");
        } else {
            asm volatile("s_waitcnt vmcnt(0)" ::: "memory");
        }
        __builtin_amdgcn_s_barrier();

        bf16x8 af[4], bf[4];
#pragma unroll
        for (int i = 0; i < 4; i++)
            af[i] = *(const bf16x8*)&sA[(wr * 64 + i * 16 + l15) * 32 + quad * 8];
#pragma unroll
        for (int j = 0; j < 4; j++)
            bf[j] = *(const bf16x8*)&sB[(wc * 64 + j * 16 + l15) * 32 + quad * 8];
#pragma unroll
        for (int i = 0; i < 4; i++)
#pragma unroll
            for (int j = 0; j < 4; j++)
                acc[i][j] = __builtin_amdgcn_mfma_f32_16x16x32_bf16(af[i], bf[j], acc[i][j], 0, 0, 0);

        __builtin_amdgcn_s_barrier();
    }
#undef QSTAGE

    float bv[4];
#pragma unroll
    for (int j = 0; j < 4; j++)
        bv[j] = (float)bias[bn + wc * 64 + j * 16 + l15];

    if (MODE == 2) {
        __hip_bfloat16* sOut = smem;
        __syncthreads();
#pragma unroll
        for (int i = 0; i < 4; i++) {
            int tl = wr * 64 + i * 16 + quad * 4;
#pragma unroll
            for (int j = 0; j < 4; j++) {
                int dl = wc * 64 + j * 16 + l15;
                union { __hip_bfloat16 e[4]; s16x4 v; } u;
#pragma unroll
                for (int r = 0; r < 4; r++)
                    u.e[r] = (__hip_bfloat16)(acc[i][j][r] + bv[j]);
                *(s16x4*)&sOut[dl * 136 + tl] = u.v;
            }
        }
        __syncthreads();
        __hip_bfloat16* VTo = (__hip_bfloat16*)C;
        const int bb = bm >> 11, tt0 = bm & 2047;
#pragma unroll
        for (int g8 = 0; g8 < 8; g8++) {
            int idx = g8 * 256 + tid;
            int dl  = idx >> 4;
            int tc  = (idx & 15) * 8;
            int dg  = bn + dl;
            bf16x8 v = *(const bf16x8*)&sOut[dl * 136 + tc];
            *(bf16x8*)&VTo[(((size_t)bb * 16 + (dg >> 6)) * 64 + (dg & 63)) * 2048 + tt0 + tc] = v;
        }
    } else {
#pragma unroll
        for (int i = 0; i < 4; i++) {
#pragma unroll
            for (int j = 0; j < 4; j++) {
                int col = bn + wc * 64 + j * 16 + l15;
#pragma unroll
                for (int r = 0; r < 4; r++) {
                    int row = bm + wr * 64 + i * 16 + quad * 4 + r;
                    float v = (acc[i][j][r] + bv[j]) * outscale;
                    if (MODE == 1) ((float*)C)[(size_t)row * N + col] = v;
                    else ((__hip_bfloat16*)C)[(size_t)row * N + col] = (__hip_bfloat16)v;
                }
            }
        }
    }
}

__global__ __launch_bounds__(256, 2) void qkv_gemm(
    const __hip_bfloat16* __restrict__ x,
    const __hip_bfloat16* __restrict__ Wq, const __hip_bfloat16* __restrict__ bq, __hip_bfloat16* __restrict__ Q,
    const __hip_bfloat16* __restrict__ Wk, const __hip_bfloat16* __restrict__ bk, __hip_bfloat16* __restrict__ Kb,
    const __hip_bfloat16* __restrict__ Wv, const __hip_bfloat16* __restrict__ bv, __hip_bfloat16* __restrict__ VT,
    int M, int N, int K)
{
    __shared__ __hip_bfloat16 smem[128 * 136];
    if (blockIdx.z == 0)
        gemm_async_body<0>(x, Wq, bq, Q, M, N, K, blockIdx.x * 128, blockIdx.y * 128, QSCALE, smem);
    else if (blockIdx.z == 1)
        gemm_async_body<0>(x, Wk, bk, Kb, M, N, K, blockIdx.x * 128, blockIdx.y * 128, 1.0f, smem);
    else
        gemm_async_body<2>(x, Wv, bv, VT, M, N, K, blockIdx.x * 128, blockIdx.y * 128, 1.0f, smem);
}

// ---------------------------------------------------------------------------
// out_gemm 64x128, 2-phase prefetch (R13, unchanged)
// ---------------------------------------------------------------------------
template <bool OF32>
__device__ __forceinline__ void gemm64_body(
    const __hip_bfloat16* __restrict__ A, const __hip_bfloat16* __restrict__ W,
    const __hip_bfloat16* __restrict__ bias, void* __restrict__ C,
    int M, int N, int K, int bm, int bn,
    __hip_bfloat16* smem)
{
    const int tid  = threadIdx.x;
    const int wave = tid >> 6;
    const int lane = tid & 63;
    const int quad = lane >> 4;
    const int l15  = lane & 15;

    const int srow = wave * 16 + (lane >> 2);
    const int scol = (lane & 3) * 8;
    const __hip_bfloat16* gA0 = A + (size_t)(bm + srow) * K + scol;
    const __hip_bfloat16* gB0 = W + (size_t)(bn + srow) * K + scol;

    f32x4 acc[4][2];
#pragma unroll
    for (int i = 0; i < 4; i++)
#pragma unroll
        for (int j = 0; j < 2; j++) acc[i][j] = (f32x4)0.0f;

#define OSTAGE(buf, k0) { \
        __hip_bfloat16* d_ = smem + (buf) * 6144; \
        async_copy16(gA0 + (k0), d_ + wave * 512); \
        async_copy16(gB0 + (k0), d_ + 2048 + wave * 512); \
        async_copy16(gB0 + (size_t)64 * K + (k0), d_ + 2048 + wave * 512 + 2048); \
    }

    const int nt = K >> 5;
    OSTAGE(0, 0);
    for (int t = 0; t < nt; ++t) {
        const int buf = t & 1;
        const __hip_bfloat16* sA = smem + buf * 6144;
        const __hip_bfloat16* sB = sA + 2048;
        if (t + 1 < nt) {
            OSTAGE(1 - buf, (t + 1) * 32);
            asm volatile("s_waitcnt vmcnt(3)" ::: "memory");
        } else {
            asm volatile("s_waitcnt vmcnt(0)" ::: "memory");
        }
        __builtin_amdgcn_s_barrier();

        bf16x8 af[4], bf[2];
#pragma unroll
        for (int i = 0; i < 4; i++)
            af[i] = *(const bf16x8*)&sA[(i * 16 + l15) * 32 + quad * 8];
#pragma unroll
        for (int j = 0; j < 2; j++)
            bf[j] = *(const bf16x8*)&sB[(wave * 32 + j * 16 + l15) * 32 + quad * 8];
#pragma unroll
        for (int i = 0; i < 4; i++)
#pragma unroll
            for (int j = 0; j < 2; j++)
                acc[i][j] = __builtin_amdgcn_mfma_f32_16x16x32_bf16(af[i], bf[j], acc[i][j], 0, 0, 0);

        __builtin_amdgcn_s_barrier();
    }
#undef OSTAGE

    float bv[2];
#pragma unroll
    for (int j = 0; j < 2; j++)
        bv[j] = (float)bias[bn + wave * 32 + j * 16 + l15];
#pragma unroll
    for (int i = 0; i < 4; i++) {
#pragma unroll
        for (int j = 0; j < 2; j++) {
            int col = bn + wave * 32 + j * 16 + l15;
#pragma unroll
            for (int r = 0; r < 4; r++) {
                int row = bm + i * 16 + quad * 4 + r;
                float v = acc[i][j][r] + bv[j];
                if (OF32) ((float*)C)[(size_t)row * N + col] = v;
                else      ((__hip_bfloat16*)C)[(size_t)row * N + col] = (__hip_bfloat16)v;
            }
        }
    }
}

__global__ __launch_bounds__(256, 2) void out_gemm(
    const __hip_bfloat16* __restrict__ A, const __hip_bfloat16* __restrict__ W,
    const __hip_bfloat16* __restrict__ bias, const void* __restrict__ origW,
    void* __restrict__ C, int M, int N, int K)
{
    __shared__ __hip_bfloat16 smem[2 * 6144];
    __shared__ int f32flag;
    if (threadIdx.x == 0) f32flag = sniff_f32(origW);
    __syncthreads();
    if (f32flag)
        gemm64_body<true>(A, W, bias, C, M, N, K, blockIdx.x * 64, blockIdx.y * 128, smem);
    else
        gemm64_body<false>(A, W, bias, C, M, N, K, blockIdx.x * 64, blockIdx.y * 128, smem);
}

// ---------------------------------------------------------------------------
// Flash attention, causal, no-max softmax, S^T formulation. R9 body, static
// LPT schedule: 640 blocks, one item each, blockIdx descending by size.
// Item = (qt, key-range); qt 12..15 split into two halves whose unnormalized
// (O,l) partials are exact-summable. PO (fp32) in dead xb; PL in dead Wqb.
// ---------------------------------------------------------------------------
#define PAD 68

__global__ __launch_bounds__(512, 2) void attn_causal(
    const __hip_bfloat16* __restrict__ Q,
    const __hip_bfloat16* __restrict__ K,
    const __hip_bfloat16* __restrict__ VT,
    __hip_bfloat16* __restrict__ O,
    float* __restrict__ PO, float* __restrict__ PL,
    int T, int D, int H)
{
    __shared__ __hip_bfloat16 sK[2][64 * PAD];
    __shared__ __hip_bfloat16 sVT[2][64 * PAD];
    __shared__ __hip_bfloat16 sPA[8][16 * PAD];   // per-wave P in A-layout

    const int tid  = threadIdx.x;
    const int wave = tid >> 6;      // 0..7
    const int lane = tid & 63;
    const int quad = lane >> 4;
    const int l15  = lane & 15;

    const int srow = tid >> 3;        // 0..63: one 16B chunk per thread
    const int sc8  = (tid & 7) * 8;

    const int rank = blockIdx.x >> 5;   // 0..19, LPT order
    const int hb   = blockIdx.x & 31;
    const int h    = hb & 15;
    const int b    = hb >> 4;
    const int qt   = QTA[rank];
    const int hf   = HFA[rank];
    const int nkt  = 2 * qt + 2;
    const int mid  = qt + 1;
    const int kt0  = (hf == 1) ? mid : 0;
    const int kt1  = (hf == 0) ? mid : nkt;

    const size_t headoff = (size_t)b * T * D + (size_t)h * 64;
    const size_t vtoff   = ((size_t)b * H + h) * 64 * (size_t)T;
    const int qbase    = qt * 128 + wave * 16;
    const int myrowmax = qbase + 15;

    // Q B-operand fragments (block-lifetime constant)
    bf16x8 qfrag[2];
#pragma unroll
    for (int kk = 0; kk < 2; kk++)
        qfrag[kk] = *(const bf16x8*)&Q[headoff +
            (size_t)(qbase + l15) * D + kk * 32 + quad * 8];

    f32x4 acc_o[4];
#pragma unroll
    for (int j = 0; j < 4; j++) acc_o[j] = (f32x4)0.0f;
    float lacc = 0.f;   // per-lane l for q = qbase + l15 (partial over quads)

    // pre-loop: stage kt0 into buf0, prefetch kt0+1
    bf16x8 pk, pv;
    pk = *(const bf16x8*)&K[headoff + (size_t)(kt0 * 64 + srow) * D + sc8];
    pv = *(const bf16x8*)&VT[vtoff + (size_t)srow * T + kt0 * 64 + sc8];
    *(bf16x8*)&sK[0][srow * PAD + sc8]  = pk;
    *(bf16x8*)&sVT[0][srow * PAD + sc8] = pv;
    if (kt0 + 1 < kt1) {
        pk = *(const bf16x8*)&K[headoff + (size_t)((kt0 + 1) * 64 + srow) * D + sc8];
        pv = *(const bf16x8*)&VT[vtoff + (size_t)srow * T + (kt0 + 1) * 64 + sc8];
    }
    __syncthreads();

    for (int kt = kt0; kt < kt1; ++kt) {
        const int cur = (kt - kt0) & 1;

        if (kt + 1 < kt1) {
            *(bf16x8*)&sK[1 - cur][srow * PAD + sc8]  = pk;
            *(bf16x8*)&sVT[1 - cur][srow * PAD + sc8] = pv;
            if (kt + 2 < kt1) {
                pk = *(const bf16x8*)&K[headoff + (size_t)((kt + 2) * 64 + srow) * D + sc8];
                pv = *(const bf16x8*)&VT[vtoff + (size_t)srow * T + (kt + 2) * 64 + sc8];
            }
        }

        if (kt * 64 <= myrowmax) {
            bf16x8 kfrag[2][4], vfrag[2][4];
#pragma unroll
            for (int kk = 0; kk < 2; kk++)
#pragma unroll
                for (int j = 0; j < 4; j++) {
                    kfrag[kk][j] = *(const bf16x8*)&sK[cur][(j * 16 + l15) * PAD + kk * 32 + quad * 8];
                    vfrag[kk][j] = *(const bf16x8*)&sVT[cur][(j * 16 + l15) * PAD + kk * 32 + quad * 8];
                }

            f32x4 st[4];
#pragma unroll
            for (int j = 0; j < 4; j++) st[j] = (f32x4)0.0f;
            __builtin_amdgcn_s_setprio(1);
#pragma unroll
            for (int kk = 0; kk < 2; kk++)
#pragma unroll
                for (int j = 0; j < 4; j++)
                    st[j] = __builtin_amdgcn_mfma_f32_16x16x32_bf16(
                        kfrag[kk][j], qfrag[kk], st[j], 0, 0, 0);
            __builtin_amdgcn_s_setprio(0);

            if (kt * 64 + 63 > qbase) {   // wave-uniform mask check (diag tile)
                const int q = qbase + l15;
#pragma unroll
                for (int j = 0; j < 4; j++) {
                    int keyb = kt * 64 + j * 16 + quad * 4;
#pragma unroll
                    for (int r = 0; r < 4; r++)
                        if (keyb + r > q) st[j][r] = -1e30f;
                }
            }

#pragma unroll
            for (int j = 0; j < 4; j++) {
                union { __hip_bfloat16 e[4]; s16x4 v; } u;
#pragma unroll
                for (int r = 0; r < 4; r++) {
                    float p = exp2f(st[j][r]);
                    lacc += p;
                    u.e[r] = (__hip_bfloat16)p;
                }
                *(s16x4*)&sPA[wave][l15 * PAD + j * 16 + quad * 4] = u.v;
            }
            // sPA wave-local: lgkmcnt orders write->read, no barrier.
            __builtin_amdgcn_s_setprio(1);
#pragma unroll
            for (int kk = 0; kk < 2; kk++) {
                bf16x8 a = *(const bf16x8*)&sPA[wave][l15 * PAD + kk * 32 + quad * 8];
#pragma unroll
                for (int j = 0; j < 4; j++)
                    acc_o[j] = __builtin_amdgcn_mfma_f32_16x16x32_bf16(
                        a, vfrag[kk][j], acc_o[j], 0, 0, 0);
            }
            __builtin_amdgcn_s_setprio(0);
        }

        __syncthreads();   // single barrier per iter
    }

    // reduce l across quads: every lane then holds full l for q=qbase+l15
    lacc += __shfl_xor(lacc, 16, 64);
    lacc += __shfl_xor(lacc, 32, 64);

    if (hf >= 0) {
        // partial: write unnormalized fp32 O + l
        const int pidx = (((b * 16 + h) * 4) + (qt - 12)) * 2 + hf;
        float* POt = PO + (size_t)pidx * 8192;
#pragma unroll
        for (int r = 0; r < 4; r++) {
            int rl = wave * 16 + quad * 4 + r;   // local row 0..127
#pragma unroll
            for (int j = 0; j < 4; j++)
                POt[rl * 64 + j * 16 + l15] = acc_o[j][r];
        }
        if (quad == 0) PL[pidx * 128 + wave * 16 + l15] = lacc;
    } else {
        // final: normalize and store bf16
#pragma unroll
        for (int r = 0; r < 4; r++) {
            float linv = 1.0f / __shfl(lacc, quad * 4 + r, 64);
            int row = qbase + quad * 4 + r;
#pragma unroll
            for (int j = 0; j < 4; j++) {
                int col = j * 16 + l15;
                O[headoff + (size_t)row * D + col] = (__hip_bfloat16)(acc_o[j][r] * linv);
            }
        }
    }
}

// ---------------------------------------------------------------------------
// Combine the 256 partial pairs (qt 12..15) into O. 128 tiles, 1 block each.
// ---------------------------------------------------------------------------
__global__ __launch_bounds__(256) void attn_combine(
    const float* __restrict__ PO, const float* __restrict__ PL,
    __hip_bfloat16* __restrict__ O, int T, int D, int H)
{
    const int tix = blockIdx.x;            // 0..127 = (b*16+h)*4 + (qt-12)
    const int qt  = 12 + (tix & 3);
    const int h   = (tix >> 2) & 15;
    const int b   = tix >> 6;
    const float* P0 = PO + (size_t)(2 * tix) * 8192;
    const float* P1 = P0 + 8192;
    const float* L0 = PL + 2 * tix * 128;
    const float* L1 = L0 + 128;
    const size_t headoff = (size_t)b * T * D + (size_t)h * 64;
    const int rowbase = qt * 128;

    for (int e = threadIdx.x; e < 8192; e += 256) {
        int rr = e >> 6, cc = e & 63;
        float linv = 1.0f / (L0[rr] + L1[rr]);
        float v = (P0[e] + P1[e]) * linv;
        O[headoff + (size_t)(rowbase + rr) * D + cc] = (__hip_bfloat16)v;
    }
}

// ---------------------------------------------------------------------------
extern "C" void kernel_launch(void* const* d_in, const int* in_sizes, int n_in,
                              void* d_out, int out_size, void* d_ws, size_t ws_size,
                              hipStream_t stream) {
    const int Bb = 2, T = 2048, D = 1024, H = 16;
    const int M = Bb * T;   // 4096

    __hip_bfloat16* w = (__hip_bfloat16*)d_ws;
    __hip_bfloat16* Q   = w;
    __hip_bfloat16* Kb  = Q   + (size_t)M * D;
    __hip_bfloat16* VT  = Kb  + (size_t)M * D;
    __hip_bfloat16* ctx = VT  + (size_t)M * D;
    __hip_bfloat16* xb  = ctx + (size_t)M * D;
    __hip_bfloat16* Wqb = xb  + (size_t)M * D;
    __hip_bfloat16* Wkb = Wqb + (size_t)D * D;
    __hip_bfloat16* Wvb = Wkb + (size_t)D * D;
    __hip_bfloat16* Wob = Wvb + (size_t)D * D;
    __hip_bfloat16* bqb = Wob + (size_t)D * D;
    __hip_bfloat16* bkb = bqb + D;
    __hip_bfloat16* bvb = bkb + D;
    __hip_bfloat16* bob = bvb + D;

    // dead-after-qkv regions reused for attn partials:
    float* PO = (float*)xb;    // 256 x 8192 f32 = 8.39 MB (== xb size exactly)
    float* PL = (float*)Wqb;   // 256 x 128 f32 = 131 KB (<= Wqb 2 MB)

    CvtPack pk;
    pk.a[0] = { d_in[0], xb,  M * D };
    pk.a[1] = { d_in[1], Wqb, D * D };
    pk.a[2] = { d_in[2], bqb, D };
    pk.a[3] = { d_in[3], Wkb, D * D };
    pk.a[4] = { d_in[4], bkb, D };
    pk.a[5] = { d_in[5], Wvb, D * D };
    pk.a[6] = { d_in[6], bvb, D };
    pk.a[7] = { d_in[7], Wob, D * D };
    pk.a[8] = { d_in[8], bob, D };

    cvt_bf16<<<dim3(512, 9), 256, 0, stream>>>(pk);
    qkv_gemm<<<dim3(M / 128, D / 128, 3), 256, 0, stream>>>(
        xb, Wqb, bqb, Q, Wkb, bkb, Kb, Wvb, bvb, VT, M, D, D);
    attn_causal<<<dim3(640, 1, 1), 512, 0, stream>>>(
        Q, Kb, VT, ctx, PO, PL, T, D, H);
    attn_combine<<<dim3(128, 1, 1), 256, 0, stream>>>(PO, PL, ctx, T, D, H);
    out_gemm<<<dim3(M / 64, D / 128), 256, 0, stream>>>(
        ctx, Wob, bob, d_in[7], d_out, M, D, D);
}